// Round 1
// baseline (380.637 us; speedup 1.0000x reference)
//
#include <hip/hip_runtime.h>
#include <math.h>

#define NXD 256
#define NCD 16
#define NTD 24
#define NPIX 65536
#define NSPLIT 4

struct c32 { float x, y; };

__device__ __forceinline__ c32 cadd(c32 a, c32 b){ return {a.x+b.x, a.y+b.y}; }
__device__ __forceinline__ c32 csub(c32 a, c32 b){ return {a.x-b.x, a.y-b.y}; }
__device__ __forceinline__ c32 cmul(c32 a, c32 b){ return {a.x*b.x - a.y*b.y, a.x*b.y + a.y*b.x}; }
__device__ __forceinline__ c32 cnegi(c32 a){ return {a.y, -a.x}; }   // -i*a

// W16^m = exp(-2*pi*i*m/16)
__constant__ float W16R_[16] = {
  1.0f, 0.9238795325f, 0.7071067812f, 0.3826834324f,
  0.0f,-0.3826834324f,-0.7071067812f,-0.9238795325f,
 -1.0f,-0.9238795325f,-0.7071067812f,-0.3826834324f,
  0.0f, 0.3826834324f, 0.7071067812f, 0.9238795325f };
__constant__ float W16I_[16] = {
  0.0f,-0.3826834324f,-0.7071067812f,-0.9238795325f,
 -1.0f,-0.9238795325f,-0.7071067812f,-0.3826834324f,
  0.0f, 0.3826834324f, 0.7071067812f, 0.9238795325f,
  1.0f, 0.9238795325f, 0.7071067812f, 0.3826834324f };

__device__ __forceinline__ int revmap(int p) { return ((p & 3) << 2) | (p >> 2); }

// 16-pt DFT in registers (radix-4 DIF x2). Input natural order; output X[k]
// stored at v[revmap(k)] (revmap is an involution).
__device__ __forceinline__ void dft16(c32 v[16]) {
  c32 y[16];
#pragma unroll
  for (int j = 0; j < 4; ++j) {
    c32 a = v[j], b = v[j+4], c = v[j+8], d = v[j+12];
    c32 t0 = cadd(a,c), t1 = csub(a,c), t2 = cadd(b,d), t3 = cnegi(csub(b,d));
    y[j] = cadd(t0,t2);
    if (j == 0) {
      y[4]  = cadd(t1,t3);
      y[8]  = csub(t0,t2);
      y[12] = csub(t1,t3);
    } else {
      c32 w1 = {W16R_[j],        W16I_[j]};
      c32 w2 = {W16R_[(2*j)&15], W16I_[(2*j)&15]};
      c32 w3 = {W16R_[(3*j)&15], W16I_[(3*j)&15]};
      y[4+j]  = cmul(cadd(t1,t3), w1);
      y[8+j]  = cmul(csub(t0,t2), w2);
      y[12+j] = cmul(csub(t1,t3), w3);
    }
  }
#pragma unroll
  for (int q = 0; q < 4; ++q) {
    c32 a = y[4*q], b = y[4*q+1], c = y[4*q+2], d = y[4*q+3];
    c32 t0 = cadd(a,c), t1 = csub(a,c), t2 = cadd(b,d), t3 = cnegi(csub(b,d));
    v[4*q+0] = cadd(t0,t2);
    v[4*q+1] = cadd(t1,t3);
    v[4*q+2] = csub(t0,t2);
    v[4*q+3] = csub(t1,t3);
  }
}

// 256-pt FFT for a 16-thread group (g = tid>>4, lane = tid&15).
// Input: v[n1] = x[16*n1 + lane]. tw[p] = W256^{lane*revmap(p)}.
// lds: 4096 c32 region shared by the block's 16 groups.
// Output: X[lane + 16*revmap(p)] in v[p]. Contains 2 block barriers; caller
// must barrier again before reusing lds.
__device__ __forceinline__ void fft256(c32 v[16], const c32 tw[16], c32* lds,
                                       int g, int lane) {
  dft16(v);
#pragma unroll
  for (int p = 0; p < 16; ++p) v[p] = cmul(v[p], tw[p]);
  __syncthreads();                 // protect previous users of lds
#pragma unroll
  for (int p = 0; p < 16; ++p) {
    int k1 = revmap(p);
    lds[g*256 + k1*16 + (lane ^ k1)] = v[p];   // XOR swizzle: banks spread
  }
  __syncthreads();
#pragma unroll
  for (int j = 0; j < 16; ++j)
    v[j] = lds[g*256 + lane*16 + (j ^ lane)];
  dft16(v);
}

// --- kernel S: smaps [nx][ny][c] (split re/im) -> smapsT[c][nx][ny] (c32) ---
__global__ __launch_bounds__(256) void kS(const float* __restrict__ sre,
                                          const float* __restrict__ sim,
                                          c32* __restrict__ smapsT) {
  __shared__ float lre[16*260];
  __shared__ float lim[16*260];
  int nx = blockIdx.x, tid = threadIdx.x;
#pragma unroll
  for (int it = 0; it < 16; ++it) {
    int e = it*256 + tid;          // e = ny*16 + c
    int ny = e >> 4, c = e & 15;
    lre[c*260 + ny] = sre[(size_t)nx*4096 + e];
    lim[c*260 + ny] = sim[(size_t)nx*4096 + e];
  }
  __syncthreads();
#pragma unroll
  for (int c = 0; c < 16; ++c) {
    c32 v = { lre[c*260 + tid], lim[c*260 + tid] };
    smapsT[(size_t)c*NPIX + nx*256 + tid] = v;
  }
}

// --- kernel M: mask [kx][ky][c][t] -> maskT[lt][ky][kx][c] for t in chunk ---
__global__ __launch_bounds__(256) void kM(const float* __restrict__ mask,
                                          float* __restrict__ maskT,
                                          int t0, int chunkT) {
  __shared__ float lm[6144];
  int kx = blockIdx.x, ky0 = blockIdx.y * 16, tid = threadIdx.x;
  const float* src = mask + (size_t)kx*98304 + (size_t)ky0*384;
#pragma unroll
  for (int it = 0; it < 24; ++it) lm[it*256 + tid] = src[it*256 + tid];
  __syncthreads();
  int total = chunkT * 256;        // chunkT * 16ky * 16c
  for (int e = tid; e < total; e += 256) {
    int c = e & 15;
    int q = e >> 4;
    int lt = q % chunkT;
    int kyl = q / chunkT;
    maskT[(((size_t)lt*256 + ky0 + kyl)*256 + kx)*16 + c]
        = lm[(kyl*16 + c)*24 + (t0 + lt)];
  }
}

// --- kernel W: bilinear warp + (-1)^{nx+ny} sign -> w[t][nx][ny] ---
__global__ __launch_bounds__(256) void kW(const float* __restrict__ ire,
                                          const float* __restrict__ iim,
                                          const float* __restrict__ flow,
                                          c32* __restrict__ w) {
  __shared__ float fl[256*49];     // per-ny stride 49 (48 + pad)
  int nx = blockIdx.x, tid = threadIdx.x;
  const float* src = flow + (size_t)nx*12288;     // [ny][d][t] slice
#pragma unroll
  for (int it = 0; it < 48; ++it) {
    int e = it*256 + tid;
    fl[(e/48)*49 + (e%48)] = src[e];
  }
  __syncthreads();
  int ny = tid;
  float s = ((nx + ny) & 1) ? -1.0f : 1.0f;
  for (int t = 0; t < NTD; ++t) {
    float fx = fl[ny*49 + t];
    float fy = fl[ny*49 + 24 + t];
    float xf = fminf(fmaxf((float)nx + fx, 0.0f), 255.0f);
    float yf = fminf(fmaxf((float)ny + fy, 0.0f), 255.0f);
    float x0f = fminf(floorf(xf), 254.0f);
    float y0f = fminf(floorf(yf), 254.0f);
    int i00 = (int)x0f * 256 + (int)y0f;
    float wx = xf - x0f, wy = yf - y0f;
    float w00 = (1.f-wx)*(1.f-wy), w01 = (1.f-wx)*wy;
    float w10 = wx*(1.f-wy),       w11 = wx*wy;
    float re = w00*ire[i00] + w01*ire[i00+1] + w10*ire[i00+256] + w11*ire[i00+257];
    float im = w00*iim[i00] + w01*iim[i00+1] + w10*iim[i00+256] + w11*iim[i00+257];
    c32 v = { re*s, im*s };
    w[(size_t)t*NPIX + nx*256 + ny] = v;
  }
}

// --- kernel A: row FFTs (along ny): Y1[lt][c][ky][nx] = FFT_ny(w_t * s_c) ---
__global__ __launch_bounds__(256) void kA(const c32* __restrict__ w,
                                          const c32* __restrict__ smapsT,
                                          c32* __restrict__ Y1, int t0) {
  __shared__ c32 lds[4368];        // 4096 for fft transpose, 256*17+16 staging
  int tid = threadIdx.x, g = tid >> 4, lane = tid & 15;
  int lt = blockIdx.y, t = t0 + lt;
  int nx0 = blockIdx.x * 16, nx = nx0 + g;
  int c0 = blockIdx.z * 4;

  c32 wr[16];
  const c32* wrow = w + (size_t)t*NPIX + nx*256;
#pragma unroll
  for (int n1 = 0; n1 < 16; ++n1) wr[n1] = wrow[n1*16 + lane];

  c32 tw[16];
#pragma unroll
  for (int p = 0; p < 16; ++p) {
    int k1 = revmap(p);
    float ang = -6.283185307179586f * (float)(lane * k1) * (1.0f/256.0f);
    float sv, cv; __sincosf(ang, &sv, &cv);
    tw[p].x = cv; tw[p].y = sv;
  }

  for (int ci = 0; ci < 4; ++ci) {
    int c = c0 + ci;
    const c32* srow = smapsT + (size_t)c*NPIX + nx*256;
    c32 v[16];
#pragma unroll
    for (int n1 = 0; n1 < 16; ++n1) v[n1] = cmul(wr[n1], srow[n1*16 + lane]);
    fft256(v, tw, lds, g, lane);
    __syncthreads();               // transpose reads done before staging write
#pragma unroll
    for (int p = 0; p < 16; ++p) {
      int ky = lane + 16*revmap(p);
      lds[ky*17 + g] = v[p];       // stride 17: ~4-way banks, not 16-way
    }
    __syncthreads();
    c32* dst = Y1 + (size_t)(lt*NCD + c)*NPIX + nx0;
#pragma unroll
    for (int it = 0; it < 16; ++it) {
      int e = it*256 + tid;        // e = ky*16 + j
      dst[(size_t)(e >> 4)*256 + (e & 15)] = lds[(e >> 4)*17 + (e & 15)];
    }
  }
}

// --- kernel B: column FFTs (along nx) + mask-weighted sum over t -> out ---
__global__ __launch_bounds__(256) void kB(const c32* __restrict__ Y1,
                                          const float* __restrict__ maskT,
                                          float* __restrict__ out,
                                          int t0, int chunkT) {
  __shared__ c32 lds[4368];
  int tid = threadIdx.x, g = tid >> 4, lane = tid & 15;   // g = coil
  int ky = blockIdx.x;

  c32 tw[16];
#pragma unroll
  for (int p = 0; p < 16; ++p) {
    int k1 = revmap(p);
    float ang = -6.283185307179586f * (float)(lane * k1) * (1.0f/256.0f);
    float sv, cv; __sincosf(ang, &sv, &cv);
    tw[p].x = cv; tw[p].y = sv;
  }

  c32 acc[16];
#pragma unroll
  for (int p = 0; p < 16; ++p) { acc[p].x = 0.f; acc[p].y = 0.f; }
  // (-1)^{kx+ky}/256 ; kx = lane + 16*k2 so parity depends only on lane
  float wsc = (((lane + ky) & 1) ? -1.0f : 1.0f) * (1.0f/256.0f);

  for (int lt = blockIdx.y; lt < chunkT; lt += NSPLIT) {
    const c32* row = Y1 + ((size_t)(lt*NCD + g)*256 + ky)*256;
    c32 v[16];
#pragma unroll
    for (int n1 = 0; n1 < 16; ++n1) v[n1] = row[n1*16 + lane];
    fft256(v, tw, lds, g, lane);
    const float* mrow = maskT + ((size_t)(t0 + lt)*256 + ky)*4096;
#pragma unroll
    for (int p = 0; p < 16; ++p) {
      int kx = lane + 16*revmap(p);
      float m = mrow[kx*16 + g] * wsc;
      acc[p].x += v[p].x * m;
      acc[p].y += v[p].y * m;
    }
  }
  __syncthreads();
#pragma unroll
  for (int p = 0; p < 16; ++p) {
    int kx = lane + 16*revmap(p);
    lds[kx*17 + g] = acc[p];
  }
  __syncthreads();
#pragma unroll
  for (int it = 0; it < 16; ++it) {
    int e = it*256 + tid;          // e = kx*16 + c
    int kx = e >> 4, c = e & 15;
    size_t o = ((size_t)kx*256 + ky)*16 + c;
    c32 vv = lds[kx*17 + c];
    atomicAdd(&out[o], vv.x);                    // real plane
    atomicAdd(&out[(size_t)NPIX*NCD + o], vv.y); // imag plane
  }
}

extern "C" void kernel_launch(void* const* d_in, const int* in_sizes, int n_in,
                              void* d_out, int out_size, void* d_ws, size_t ws_size,
                              hipStream_t stream) {
  const float* ire  = (const float*)d_in[0];
  const float* iim  = (const float*)d_in[1];
  const float* mask = (const float*)d_in[2];
  const float* sre  = (const float*)d_in[3];
  const float* sim  = (const float*)d_in[4];
  const float* flow = (const float*)d_in[5];
  float* out = (float*)d_out;

  char* ws = (char*)d_ws;
  const size_t smapsT_b = (size_t)NCD * NPIX * sizeof(c32);   // 8 MB
  const size_t w_b      = (size_t)NTD * NPIX * sizeof(c32);   // 12.6 MB
  c32* smapsT = (c32*)ws;
  c32* wbuf   = (c32*)(ws + smapsT_b);
  size_t base = smapsT_b + w_b;
  size_t rem  = (ws_size > base) ? ws_size - base : 0;

  const size_t maskT_per_t = (size_t)NPIX * NCD * sizeof(float); // 4 MB
  const size_t y1_per_t    = (size_t)NCD * NPIX * sizeof(c32);   // 8 MB
  int chunk = 1;
  const int cands[8] = {24, 12, 8, 6, 4, 3, 2, 1};
  for (int i = 0; i < 8; ++i) {
    if ((size_t)cands[i] * (maskT_per_t + y1_per_t) <= rem) { chunk = cands[i]; break; }
  }
  float* maskT = (float*)(ws + base);
  c32*   Y1    = (c32*)(ws + base + (size_t)chunk * maskT_per_t);

  hipMemsetAsync(d_out, 0, (size_t)out_size * sizeof(float), stream);
  kS<<<256, 256, 0, stream>>>(sre, sim, smapsT);
  kW<<<256, 256, 0, stream>>>(ire, iim, flow, wbuf);
  for (int t0 = 0; t0 < NTD; t0 += chunk) {
    kM<<<dim3(256, 16), 256, 0, stream>>>(mask, maskT, t0, chunk);
    kA<<<dim3(16, chunk, 4), 256, 0, stream>>>(wbuf, smapsT, Y1, t0);
    kB<<<dim3(256, NSPLIT), 256, 0, stream>>>(Y1, maskT, out, t0, chunk);
  }
}

// Round 3
// 329.849 us; speedup vs baseline: 1.1540x; 1.1540x over previous
//
#include <hip/hip_runtime.h>
#include <math.h>

#define NCD 16
#define NTD 24
#define NPIX 65536

struct c32 { float x, y; };

__device__ __forceinline__ c32 cadd(c32 a, c32 b){ return {a.x+b.x, a.y+b.y}; }
__device__ __forceinline__ c32 csub(c32 a, c32 b){ return {a.x-b.x, a.y-b.y}; }
__device__ __forceinline__ c32 cmul(c32 a, c32 b){ return {a.x*b.x - a.y*b.y, a.x*b.y + a.y*b.x}; }
__device__ __forceinline__ c32 cnegi(c32 a){ return {a.y, -a.x}; }   // -i*a

__device__ __forceinline__ unsigned short f2h(float f) {
  return __builtin_bit_cast(unsigned short, (_Float16)f);
}
__device__ __forceinline__ float h2f(unsigned short s) {
  return (float)__builtin_bit_cast(_Float16, s);
}

__constant__ float W16R_[16] = {
  1.0f, 0.9238795325f, 0.7071067812f, 0.3826834324f,
  0.0f,-0.3826834324f,-0.7071067812f,-0.9238795325f,
 -1.0f,-0.9238795325f,-0.7071067812f,-0.3826834324f,
  0.0f, 0.3826834324f, 0.7071067812f, 0.9238795325f };
__constant__ float W16I_[16] = {
  0.0f,-0.3826834324f,-0.7071067812f,-0.9238795325f,
 -1.0f,-0.9238795325f,-0.7071067812f,-0.3826834324f,
  0.0f, 0.3826834324f, 0.7071067812f, 0.9238795325f,
  1.0f, 0.9238795325f, 0.7071067812f, 0.3826834324f };

__device__ __forceinline__ int revmap(int p) { return ((p & 3) << 2) | (p >> 2); }

// 16-pt DFT in registers. Output X[k] at v[revmap(k)].
__device__ __forceinline__ void dft16(c32 v[16]) {
  c32 y[16];
#pragma unroll
  for (int j = 0; j < 4; ++j) {
    c32 a = v[j], b = v[j+4], c = v[j+8], d = v[j+12];
    c32 t0 = cadd(a,c), t1 = csub(a,c), t2 = cadd(b,d), t3 = cnegi(csub(b,d));
    y[j] = cadd(t0,t2);
    if (j == 0) {
      y[4]  = cadd(t1,t3);
      y[8]  = csub(t0,t2);
      y[12] = csub(t1,t3);
    } else {
      c32 w1 = {W16R_[j],        W16I_[j]};
      c32 w2 = {W16R_[(2*j)&15], W16I_[(2*j)&15]};
      c32 w3 = {W16R_[(3*j)&15], W16I_[(3*j)&15]};
      y[4+j]  = cmul(cadd(t1,t3), w1);
      y[8+j]  = cmul(csub(t0,t2), w2);
      y[12+j] = cmul(csub(t1,t3), w3);
    }
  }
#pragma unroll
  for (int q = 0; q < 4; ++q) {
    c32 a = y[4*q], b = y[4*q+1], c = y[4*q+2], d = y[4*q+3];
    c32 t0 = cadd(a,c), t1 = csub(a,c), t2 = cadd(b,d), t3 = cnegi(csub(b,d));
    v[4*q+0] = cadd(t0,t2);
    v[4*q+1] = cadd(t1,t3);
    v[4*q+2] = csub(t0,t2);
    v[4*q+3] = csub(t1,t3);
  }
}

// 256-pt FFT for a 16-thread group. Input v[n1]=x[16*n1+lane];
// output X[lane+16*revmap(p)] in v[p]. Uses lds[0..4096) (c32 only).
// 2 barriers inside; first barrier protects previous users of lds.
__device__ __forceinline__ void fft256(c32 v[16], const c32 tw[16], c32* lds,
                                       int g, int lane) {
  dft16(v);
#pragma unroll
  for (int p = 0; p < 16; ++p) v[p] = cmul(v[p], tw[p]);
  __syncthreads();
#pragma unroll
  for (int p = 0; p < 16; ++p) {
    int k1 = revmap(p);
    lds[g*256 + k1*16 + (lane ^ k1)] = v[p];
  }
  __syncthreads();
#pragma unroll
  for (int j = 0; j < 16; ++j)
    v[j] = lds[g*256 + lane*16 + (j ^ lane)];
  dft16(v);
}

// --- kS: smaps [nx][ny][c] (split re/im) -> smapsT[c][nx][ny] (c32) ---
__global__ __launch_bounds__(256) void kS(const float* __restrict__ sre,
                                          const float* __restrict__ sim,
                                          c32* __restrict__ smapsT) {
  __shared__ float lre[16*260];
  __shared__ float lim[16*260];
  int nx = blockIdx.x, tid = threadIdx.x;
#pragma unroll
  for (int it = 0; it < 16; ++it) {
    int e = it*256 + tid;          // e = ny*16 + c
    int ny = e >> 4, c = e & 15;
    lre[c*260 + ny] = sre[(size_t)nx*4096 + e];
    lim[c*260 + ny] = sim[(size_t)nx*4096 + e];
  }
  __syncthreads();
#pragma unroll
  for (int c = 0; c < 16; ++c) {
    c32 v = { lre[c*260 + tid], lim[c*260 + tid] };
    smapsT[(size_t)c*NPIX + nx*256 + tid] = v;
  }
}

// --- kW: bilinear warp + (-1)^{nx+ny} sign -> w[t][nx][ny] (c32) ---
__global__ __launch_bounds__(256) void kW(const float* __restrict__ ire,
                                          const float* __restrict__ iim,
                                          const float* __restrict__ flow,
                                          c32* __restrict__ w) {
  __shared__ float fl[256*49];
  int nx = blockIdx.x, tid = threadIdx.x;
  const float* src = flow + (size_t)nx*12288;     // [ny][d][t] slice
#pragma unroll
  for (int it = 0; it < 48; ++it) {
    int e = it*256 + tid;
    fl[(e/48)*49 + (e%48)] = src[e];
  }
  __syncthreads();
  int ny = tid;
  float s = ((nx + ny) & 1) ? -1.0f : 1.0f;
  for (int t = 0; t < NTD; ++t) {
    float fx = fl[ny*49 + t];
    float fy = fl[ny*49 + 24 + t];
    float xf = fminf(fmaxf((float)nx + fx, 0.0f), 255.0f);
    float yf = fminf(fmaxf((float)ny + fy, 0.0f), 255.0f);
    float x0f = fminf(floorf(xf), 254.0f);
    float y0f = fminf(floorf(yf), 254.0f);
    int i00 = (int)x0f * 256 + (int)y0f;
    float wx = xf - x0f, wy = yf - y0f;
    float w00 = (1.f-wx)*(1.f-wy), w01 = (1.f-wx)*wy;
    float w10 = wx*(1.f-wy),       w11 = wx*wy;
    float re = w00*ire[i00] + w01*ire[i00+1] + w10*ire[i00+256] + w11*ire[i00+257];
    float im = w00*iim[i00] + w01*iim[i00+1] + w10*iim[i00+256] + w11*iim[i00+257];
    c32 v = { re*s, im*s };
    w[(size_t)t*NPIX + nx*256 + ny] = v;
  }
}

// --- kM: mask [kx][ky][c][t] -> fp16 maskTh[lt][ky][c][pos], pos=nibbleswap(kx)
__global__ __launch_bounds__(256) void kM(const float* __restrict__ mask,
                                          unsigned int* __restrict__ maskTh,
                                          int t0, int chunkT) {
  __shared__ unsigned short lm[256*49];
  int ky = blockIdx.x, c0 = blockIdx.y*2, tid = threadIdx.x;
  int nct = 2*chunkT;              // <= 48
  int total = 256*nct;
  for (int e = tid; e < total; e += 256) {
    int kx = e / nct, ctl = e - kx*nct;
    int hi = (ctl >= chunkT) ? 1 : 0;
    int cc = c0 + hi;
    int tt = t0 + ctl - hi*chunkT;
    lm[kx*49 + ctl] = f2h(mask[(size_t)kx*98304 + ky*384 + cc*24 + tt]);
  }
  __syncthreads();
  int wtotal = nct*128;
  for (int e = tid; e < wtotal; e += 256) {
    int ctl = e >> 7;
    int posh = (e & 127) * 2;      // even pos; write pair (posh, posh+1) as uint
    int hi = (ctl >= chunkT) ? 1 : 0;
    int cc = c0 + hi;
    int ltt = ctl - hi*chunkT;
    int kxa = ((posh & 15) << 4) | (posh >> 4);
    int kxb = (((posh+1) & 15) << 4) | ((posh+1) >> 4);
    unsigned int a = lm[kxa*49 + ctl], b = lm[kxb*49 + ctl];
    // uint index: (plane*256 + posh)/2
    size_t base = (((((size_t)ltt*256 + ky)*16 + cc) << 8) + posh) >> 1;
    maskTh[base] = a | (b << 16);
  }
}

// --- kA: row FFTs along ny -> Y1h[lt][c][ky][nx] as packed half2 (uint) ---
__global__ __launch_bounds__(256) void kA(const c32* __restrict__ w,
                                          const c32* __restrict__ smapsT,
                                          unsigned int* __restrict__ Y1h, int t0) {
  __shared__ c32 lds[4096];              // 32 KB fft workspace (c32 only)
  __shared__ unsigned int stage[4096];   // 16 KB staging (uint only)
  int tid = threadIdx.x, g = tid >> 4, lane = tid & 15;
  int lt = blockIdx.y, t = t0 + lt;
  int nx0 = blockIdx.x*16, nx = nx0 + g;
  int c0 = blockIdx.z*4;

  c32 wr[16];
  const c32* wrow = w + (size_t)t*NPIX + nx*256;
#pragma unroll
  for (int n1 = 0; n1 < 16; ++n1) wr[n1] = wrow[n1*16 + lane];

  c32 tw[16];
#pragma unroll
  for (int p = 0; p < 16; ++p) {
    int k1 = revmap(p);
    float ang = -6.283185307179586f * (float)(lane * k1) * (1.0f/256.0f);
    float sv, cv; __sincosf(ang, &sv, &cv);
    tw[p].x = cv; tw[p].y = sv;
  }

  for (int ci = 0; ci < 4; ++ci) {
    int c = c0 + ci;
    const c32* srow = smapsT + (size_t)c*NPIX + nx*256;
    c32 v[16];
#pragma unroll
    for (int n1 = 0; n1 < 16; ++n1) v[n1] = cmul(wr[n1], srow[n1*16 + lane]);
    fft256(v, tw, lds, g, lane);
    // stage is disjoint memory from lds: safe to write while laggards still
    // read lds inside fft256. Reuse across ci protected by fft256's barriers.
#pragma unroll
    for (int p = 0; p < 16; ++p) {
      int ky = lane + 16*revmap(p);    // ky & 15 == lane
      unsigned int pk = (unsigned int)f2h(v[p].x)
                      | ((unsigned int)f2h(v[p].y) << 16);
      stage[ky*16 + (g ^ lane)] = pk;
    }
    __syncthreads();
    unsigned int* dst = Y1h + (((size_t)lt*16 + c) << 16) + nx0;
#pragma unroll
    for (int it = 0; it < 16; ++it) {
      int e = it*256 + tid;
      int ky = e >> 4, j = e & 15;
      dst[(size_t)ky*256 + j] = stage[ky*16 + (j ^ (ky & 15))];
    }
  }
}

// --- kB: column FFTs + mask-weighted t-reduction -> out, no atomics ---
__global__ __launch_bounds__(256) void kB(const unsigned int* __restrict__ Y1h,
                                          const unsigned int* __restrict__ maskTh,
                                          float* __restrict__ out,
                                          int chunkT, int accum) {
  __shared__ c32 lds[4096];        // 32 KB
  int tid = threadIdx.x, g = tid >> 4, lane = tid & 15;
  int ci = g & 3, tp = g >> 2;     // 4 coils x 4 t-phases
  int cq = blockIdx.x, ky = blockIdx.y;
  int c = cq*4 + ci;

  c32 tw[16];
#pragma unroll
  for (int p = 0; p < 16; ++p) {
    int k1 = revmap(p);
    float ang = -6.283185307179586f * (float)(lane * k1) * (1.0f/256.0f);
    float sv, cv; __sincosf(ang, &sv, &cv);
    tw[p].x = cv; tw[p].y = sv;
  }

  c32 acc[16];
#pragma unroll
  for (int p = 0; p < 16; ++p) { acc[p].x = 0.f; acc[p].y = 0.f; }
  float wsc = (((lane + ky) & 1) ? -1.0f : 1.0f) * (1.0f/256.0f);

  int iters = (chunkT + 3) >> 2;
  for (int ii = 0; ii < iters; ++ii) {
    int lt = tp + 4*ii;
    bool act = lt < chunkT;
    int lts = act ? lt : 0;        // inactive threads read valid plane 0
    const unsigned int* row = Y1h + ((size_t)(lts*16 + c)*256 + ky)*256;
    const unsigned int* mp = maskTh
        + (((((size_t)lts*256 + ky)*16 + c) << 8) >> 1) + lane*8;
    unsigned int mu[8];
#pragma unroll
    for (int q = 0; q < 8; ++q) mu[q] = mp[q];
    c32 v[16];
#pragma unroll
    for (int n1 = 0; n1 < 16; ++n1) {
      unsigned int uu = row[n1*16 + lane];
      v[n1].x = h2f((unsigned short)(uu & 0xffffu));
      v[n1].y = h2f((unsigned short)(uu >> 16));
    }
    fft256(v, tw, lds, g, lane);
    if (act) {
#pragma unroll
      for (int p = 0; p < 16; ++p) {
        int j = revmap(p);         // pos = lane*16 + j holds kx = lane + 16*j
        unsigned int um = mu[j >> 1];
        unsigned short us = (j & 1) ? (unsigned short)(um >> 16)
                                    : (unsigned short)(um & 0xffffu);
        float m = h2f(us) * wsc;
        acc[p].x += v[p].x * m;
        acc[p].y += v[p].y * m;
      }
    }
  }
  __syncthreads();
#pragma unroll
  for (int p = 0; p < 16; ++p) lds[g*256 + p*16 + lane] = acc[p];
  __syncthreads();
  // thread tid = kx; gather 4 tp partials x 4 coils, write float4 per plane
  int kx = tid;
  int lane2 = kx & 15, pp = revmap(kx >> 4);
  float vre[4], vim[4];
#pragma unroll
  for (int c2 = 0; c2 < 4; ++c2) {
    float sx = 0.f, sy = 0.f;
#pragma unroll
    for (int t2 = 0; t2 < 4; ++t2) {
      c32 a = lds[(t2*4 + c2)*256 + pp*16 + lane2];
      sx += a.x; sy += a.y;
    }
    vre[c2] = sx; vim[c2] = sy;
  }
  size_t o = (((size_t)kx << 8) + ky)*16 + cq*4;
  float4* pre = (float4*)(out + o);
  float4* pim = (float4*)(out + (size_t)NPIX*NCD + o);
  float4 R = {vre[0], vre[1], vre[2], vre[3]};
  float4 I = {vim[0], vim[1], vim[2], vim[3]};
  if (accum) {
    float4 r0 = *pre, i0 = *pim;
    R.x += r0.x; R.y += r0.y; R.z += r0.z; R.w += r0.w;
    I.x += i0.x; I.y += i0.y; I.z += i0.z; I.w += i0.w;
  }
  *pre = R; *pim = I;
}

extern "C" void kernel_launch(void* const* d_in, const int* in_sizes, int n_in,
                              void* d_out, int out_size, void* d_ws, size_t ws_size,
                              hipStream_t stream) {
  const float* ire  = (const float*)d_in[0];
  const float* iim  = (const float*)d_in[1];
  const float* mask = (const float*)d_in[2];
  const float* sre  = (const float*)d_in[3];
  const float* sim  = (const float*)d_in[4];
  const float* flow = (const float*)d_in[5];
  float* out = (float*)d_out;

  char* ws = (char*)d_ws;
  const size_t smapsT_b = (size_t)NCD * NPIX * sizeof(c32);   // 8 MB
  const size_t w_b      = (size_t)NTD * NPIX * sizeof(c32);   // 12.6 MB
  c32* smapsT = (c32*)ws;
  c32* wbuf   = (c32*)(ws + smapsT_b);
  size_t base = smapsT_b + w_b;
  size_t rem  = (ws_size > base) ? ws_size - base : 0;

  const size_t maskT_per_t = (size_t)NPIX * NCD * 2;          // 2 MB (fp16)
  const size_t y1_per_t    = (size_t)NCD * NPIX * 4;          // 4 MB (half2)
  int chunk = 1;
  const int cands[8] = {24, 12, 8, 6, 4, 3, 2, 1};
  for (int i = 0; i < 8; ++i) {
    if ((size_t)cands[i] * (maskT_per_t + y1_per_t) <= rem) { chunk = cands[i]; break; }
  }
  unsigned int* maskTh = (unsigned int*)(ws + base);
  unsigned int* Y1h    = (unsigned int*)(ws + base + (size_t)chunk * maskT_per_t);

  kS<<<256, 256, 0, stream>>>(sre, sim, smapsT);
  kW<<<256, 256, 0, stream>>>(ire, iim, flow, wbuf);
  for (int t0 = 0; t0 < NTD; t0 += chunk) {
    kM<<<dim3(256, 8), 256, 0, stream>>>(mask, maskTh, t0, chunk);
    kA<<<dim3(16, chunk, 4), 256, 0, stream>>>(wbuf, smapsT, Y1h, t0);
    kB<<<dim3(4, 256), 256, 0, stream>>>(Y1h, maskTh, out, chunk, t0 > 0 ? 1 : 0);
  }
}